// Round 3
// baseline (749.369 us; speedup 1.0000x reference)
//
#include <hip/hip_runtime.h>

typedef __attribute__((ext_vector_type(4))) float f32x4;
typedef __attribute__((ext_vector_type(16))) float f32x16;
typedef __attribute__((ext_vector_type(8))) short bf16x8;
typedef __attribute__((ext_vector_type(4))) unsigned short u16x4;
typedef __attribute__((ext_vector_type(2))) unsigned short u16x2;
typedef __attribute__((ext_vector_type(4))) unsigned int u32x4;

#define SEQ 2048
#define DMODEL 4096

__device__ __forceinline__ unsigned short f2bf(float f) {
  unsigned int u = __float_as_uint(f);
  u += 0x7FFFu + ((u >> 16) & 1u);   // RNE
  return (unsigned short)(u >> 16);
}

__device__ __forceinline__ void gload_lds16(const unsigned short* g, unsigned short* l) {
  __builtin_amdgcn_global_load_lds(
      (const __attribute__((address_space(1))) unsigned int*)g,
      (__attribute__((address_space(3))) unsigned int*)l, 16, 0, 0);
}

__device__ __forceinline__ unsigned int cvt_pk_bf16(float lo, float hi) {
  unsigned int r;
  asm("v_cvt_pk_bf16_f32 %0, %1, %2" : "=v"(r) : "v"(lo), "v"(hi));
  return r;
}

// ---------------- fused fp32 -> bf16 converts (x, wq, wk, wv) ----------------
__global__ __launch_bounds__(256) void cvt_bf16_multi(
    const float* __restrict__ s0, unsigned short* __restrict__ d0, int n0,
    const float* __restrict__ s1, unsigned short* __restrict__ d1, int n1,
    const float* __restrict__ s2, unsigned short* __restrict__ d2, int n2,
    const float* __restrict__ s3, unsigned short* __restrict__ d3, int n3) {
  int i = blockIdx.x * 256 + threadIdx.x;
  const float* s; unsigned short* d; int j = i;
  if (j < n0) { s = s0; d = d0; }
  else if ((j -= n0) < n1) { s = s1; d = d1; }
  else if ((j -= n1) < n2) { s = s2; d = d2; }
  else if ((j -= n2) < n3) { s = s3; d = d3; }
  else return;
  f32x4 v = *(const f32x4*)(s + (size_t)j * 4);
  u16x4 o;
  o[0] = f2bf(v[0]); o[1] = f2bf(v[1]); o[2] = f2bf(v[2]); o[3] = f2bf(v[3]);
  *(u16x4*)(d + (size_t)j * 4) = o;
}

__global__ __launch_bounds__(256) void cvt_bf16(const float* __restrict__ in,
                                                unsigned short* __restrict__ out, int n4) {
  int i = blockIdx.x * 256 + threadIdx.x;
  if (i >= n4) return;
  f32x4 v = *(const f32x4*)(in + (size_t)i * 4);
  u16x4 o;
  o[0] = f2bf(v[0]); o[1] = f2bf(v[1]); o[2] = f2bf(v[2]); o[3] = f2bf(v[3]);
  *(u16x4*)(out + (size_t)i * 4) = o;
}

// ---------------- bf16 GEMM body, C = A[M,K] * B[N,K]^T, K=4096 ----------------
__device__ __forceinline__ void gemm_bt_body(const unsigned short* __restrict__ A,
                                             const unsigned short* __restrict__ B,
                                             float* __restrict__ C, int N,
                                             int bm, int bn) {
  __shared__ unsigned short As[128 * 64];
  __shared__ unsigned short Bs[128 * 64];
  const int K = 4096;
  const int t = threadIdx.x;
  const int lane = t & 63, w = t >> 6;
  const int wm = w >> 1, wn = w & 1;
  const int g = lane >> 4, q = lane & 15;

  const int srow = t >> 3;
  const int slb = (t & 7) ^ (srow & 7);
  const unsigned short* gA = A + (size_t)(bm * 128 + srow) * K + slb * 8;
  const unsigned short* gB = B + (size_t)(bn * 128 + srow) * K + slb * 8;
  unsigned short* lA = As + t * 8;
  unsigned short* lB = Bs + t * 8;

  f32x4 acc[4][4];
  for (int i = 0; i < 4; ++i)
    for (int j = 0; j < 4; ++j)
      for (int r = 0; r < 4; ++r) acc[i][j][r] = 0.f;

  for (int k0 = 0; k0 < K; k0 += 64) {
#pragma unroll
    for (int i = 0; i < 4; ++i) {
      gload_lds16(gA + (size_t)i * 32 * K + k0, lA + i * 2048);
      gload_lds16(gB + (size_t)i * 32 * K + k0, lB + i * 2048);
    }
    __syncthreads();
#pragma unroll
    for (int kk = 0; kk < 2; ++kk) {
      bf16x8 af[4], bfr[4];
#pragma unroll
      for (int i = 0; i < 4; ++i) {
        const int ra = wm * 64 + i * 16 + q;
        af[i] = *(const bf16x8*)&As[ra * 64 + (((kk * 4 + g) ^ (ra & 7)) * 8)];
        const int rb = wn * 64 + i * 16 + q;
        bfr[i] = *(const bf16x8*)&Bs[rb * 64 + (((kk * 4 + g) ^ (rb & 7)) * 8)];
      }
#pragma unroll
      for (int i = 0; i < 4; ++i)
#pragma unroll
        for (int j = 0; j < 4; ++j)
          acc[i][j] = __builtin_amdgcn_mfma_f32_16x16x32_bf16(af[i], bfr[j], acc[i][j], 0, 0, 0);
    }
    __syncthreads();
  }

  const int crow0 = bm * 128 + wm * 64 + g * 4;
  const int ccol0 = bn * 128 + wn * 64 + q;
#pragma unroll
  for (int i = 0; i < 4; ++i)
#pragma unroll
    for (int j = 0; j < 4; ++j) {
      float* cp = C + (size_t)(crow0 + i * 16) * N + ccol0 + j * 16;
#pragma unroll
      for (int r = 0; r < 4; ++r) cp[(size_t)r * N] = acc[i][j][r];
    }
}

__global__ __launch_bounds__(256) void gemm_bt(const unsigned short* __restrict__ A,
                                               const unsigned short* __restrict__ B,
                                               float* __restrict__ C, int N) {
  gemm_bt_body(A, B, C, N, blockIdx.x, blockIdx.y);
}

// fused K+V projection: grid (16, 16); bn<8 -> K, else V (both N=1024)
__global__ __launch_bounds__(256) void gemm_bt_kv(const unsigned short* __restrict__ A,
                                                  const unsigned short* __restrict__ BK,
                                                  const unsigned short* __restrict__ BV,
                                                  float* __restrict__ CK,
                                                  float* __restrict__ CV) {
  const int bn = blockIdx.y;
  if (bn < 8) gemm_bt_body(A, BK, CK, 1024, blockIdx.x, bn);
  else        gemm_bt_body(A, BV, CV, 1024, blockIdx.x, bn - 8);
}

// ---------------- RoPE + relayout to head-major bf16 [h][S][128] ----------------
__global__ __launch_bounds__(256) void rope_relayout(const float* __restrict__ X,
                                                     const float* __restrict__ cosT,
                                                     const float* __restrict__ sinT,
                                                     unsigned short* __restrict__ out,
                                                     int nheads, int ld) {
  int idx = blockIdx.x * 256 + threadIdx.x;
  int m = idx & 63;
  int h = (idx >> 6) % nheads;
  int s = idx / (nheads * 64);
  if (s >= SEQ) return;
  const float* xp = X + (size_t)s * ld + h * 128 + 2 * m;
  float re = xp[0], im = xp[1];
  float c = cosT[s * 64 + m], sn = sinT[s * 64 + m];
  u16x2 o;
  o[0] = f2bf(re * c - im * sn);
  o[1] = f2bf(re * sn + im * c);
  *(u16x2*)(out + ((size_t)h * SEQ + s) * 128 + 2 * m) = o;
}

// ---------------- V transpose: Vf[s][1024] f32 -> VT[d][s] bf16 ----------------
__global__ __launch_bounds__(256) void v_transpose(const float* __restrict__ Vf,
                                                   unsigned short* __restrict__ VT) {
  __shared__ float tile[32][33];
  int s0 = blockIdx.x * 32, d0 = blockIdx.y * 32;
  int tx = threadIdx.x & 31, ty = threadIdx.x >> 5;
  for (int i = ty; i < 32; i += 8)
    tile[i][tx] = Vf[(size_t)(s0 + i) * 1024 + d0 + tx];
  __syncthreads();
  for (int i = ty; i < 32; i += 8)
    VT[(size_t)(d0 + i) * SEQ + s0 + tx] = f2bf(tile[tx][i]);
}

// ---------------- Flash attention, balanced split+pair, 2-wave blocks ----------
// 1024 blocks x 128 thr. Block b: kv-head = b&7 (XCD-local), q-head sub (b>>3)&3,
// pair p = b>>5. Tiles A=p, B=63-p (32 q-rows each). Each tile's causal range is
// split in half across the two waves; pairing makes every wave ~32-33 iters.
// Per-tile merge of (m,l,acc) partials through LDS.
__global__ __launch_bounds__(128, 4) void attn_kernel(const unsigned short* __restrict__ Qh,
                                                      const unsigned short* __restrict__ Kh,
                                                      const unsigned short* __restrict__ VT,
                                                      unsigned short* __restrict__ Out) {
  __shared__ float mbuf[2][32];
  __shared__ float lbuf[2][32];
  __shared__ float abuf[64 * 64];

  const int b = blockIdx.x;
  const int h = (b & 7) * 4 + ((b >> 3) & 3);
  const int p = b >> 5;
  const int kvh = h >> 2;
  const int t = threadIdx.x, w = t >> 6, lane = t & 63;
  const int ln = lane & 31, hi = lane >> 5;

  const unsigned short* Kp = Kh + ((size_t)kvh * SEQ + ln) * 128 + hi * 8;
  const unsigned short* Vp = VT + ((size_t)(kvh * 128 + ln)) * SEQ + hi * 8;
  const float SCL = 0.08838834764831845f * 1.44269504088896f;  // scale * log2(e)

  const int nA = p + 1, nB = 64 - p;
  const int loA = (nA + 1) >> 1, loB = (nB + 1) >> 1;

  for (int s = 0; s < 2; ++s) {
    const int tile = (s == 0) ? p : 63 - p;
    const int q0 = tile * 32;
    int kbeg, kend;
    if (s == 0) { kbeg = w ? loA : 0;  kend = w ? nA : loA; }
    else        { kbeg = w ? 0 : loB;  kend = w ? loB : nB; }

    const unsigned short* Qp = Qh + ((size_t)h * SEQ + q0 + ln) * 128 + hi * 8;
    bf16x8 qf[8];
#pragma unroll
    for (int ds = 0; ds < 8; ++ds) qf[ds] = *(const bf16x8*)(Qp + ds * 16);

    f32x16 acc[4];
#pragma unroll
    for (int dt = 0; dt < 4; ++dt)
#pragma unroll
      for (int r = 0; r < 16; ++r) acc[dt][r] = 0.f;
    float m_run = -1e30f, l_run = 0.f;

    for (int kc = kbeg; kc < kend; ++kc) {
      const int k0 = kc * 32;
      // V frags issued early (latency hides under QK^T + softmax)
      bf16x8 vf[4][2];
#pragma unroll
      for (int dt = 0; dt < 4; ++dt)
#pragma unroll
        for (int ks = 0; ks < 2; ++ks)
          vf[dt][ks] = *(const bf16x8*)(Vp + (size_t)dt * 32 * SEQ + k0 + ks * 16);

      // QK^T (two independent chains)
      bf16x8 kf[8];
      const unsigned short* kp = Kp + (size_t)k0 * 128;
#pragma unroll
      for (int ds = 0; ds < 8; ++ds) kf[ds] = *(const bf16x8*)(kp + ds * 16);
      f32x16 s0v, s1v;
#pragma unroll
      for (int r = 0; r < 16; ++r) { s0v[r] = 0.f; s1v[r] = 0.f; }
#pragma unroll
      for (int ds = 0; ds < 4; ++ds) {
        s0v = __builtin_amdgcn_mfma_f32_32x32x16_bf16(kf[ds], qf[ds], s0v, 0, 0, 0);
        s1v = __builtin_amdgcn_mfma_f32_32x32x16_bf16(kf[ds + 4], qf[ds + 4], s1v, 0, 0, 0);
      }

      // mask + in-register softmax (rows k = (r&3)+8*(r>>2)+4*hi)
      float sv[16];
#pragma unroll
      for (int r = 0; r < 16; ++r) {
        int kg = k0 + (r & 3) + 8 * (r >> 2) + 4 * hi;
        float vv = s0v[r] + s1v[r];
        sv[r] = (kg <= q0 + ln) ? vv : -1e30f;
      }
      float mx01 = fmaxf(sv[0], sv[1]), mx23 = fmaxf(sv[2], sv[3]);
      float mx45 = fmaxf(sv[4], sv[5]), mx67 = fmaxf(sv[6], sv[7]);
      float mx89 = fmaxf(sv[8], sv[9]), mxab = fmaxf(sv[10], sv[11]);
      float mxcd = fmaxf(sv[12], sv[13]), mxef = fmaxf(sv[14], sv[15]);
      float pm = fmaxf(fmaxf(fmaxf(mx01, mx23), fmaxf(mx45, mx67)),
                       fmaxf(fmaxf(mx89, mxab), fmaxf(mxcd, mxef)));
      pm = fmaxf(pm, __shfl_xor(pm, 32, 64));

      // defer-max rescale (THR = 8 log2-units)
      if (__any((pm - m_run) * SCL > 8.f)) {
        float m_new = fmaxf(m_run, pm);
        float corr = exp2f((m_run - m_new) * SCL);
        l_run *= corr;
#pragma unroll
        for (int r = 0; r < 16; ++r) {
          float cf = __shfl(corr, (r & 3) + 8 * (r >> 2) + 4 * hi, 64);
          acc[0][r] *= cf; acc[1][r] *= cf; acc[2][r] *= cf; acc[3][r] *= cf;
        }
        m_run = m_new;
      }

      // P = exp2((s - m) * SCL), row-sum
      float pv[16];
#pragma unroll
      for (int r = 0; r < 16; ++r) pv[r] = exp2f((sv[r] - m_run) * SCL);
      float a0 = (pv[0] + pv[1]) + (pv[2] + pv[3]);
      float a1 = (pv[4] + pv[5]) + (pv[6] + pv[7]);
      float a2 = (pv[8] + pv[9]) + (pv[10] + pv[11]);
      float a3 = (pv[12] + pv[13]) + (pv[14] + pv[15]);
      float ps = (a0 + a1) + (a2 + a3);
      ps += __shfl_xor(ps, 32, 64);
      l_run += ps;

      // pack P into PV A-frags: k = 16*ks + 8*hi + j
      bf16x8 pa[2];
#pragma unroll
      for (int ks = 0; ks < 2; ++ks) {
        unsigned int X0 = cvt_pk_bf16(pv[8 * ks + 0], pv[8 * ks + 1]);
        unsigned int X1 = cvt_pk_bf16(pv[8 * ks + 2], pv[8 * ks + 3]);
        unsigned int Y0 = cvt_pk_bf16(pv[8 * ks + 4], pv[8 * ks + 5]);
        unsigned int Y1 = cvt_pk_bf16(pv[8 * ks + 6], pv[8 * ks + 7]);
        unsigned int sX0 = (unsigned int)__shfl_xor((int)X0, 32, 64);
        unsigned int sX1 = (unsigned int)__shfl_xor((int)X1, 32, 64);
        unsigned int sY0 = (unsigned int)__shfl_xor((int)Y0, 32, 64);
        unsigned int sY1 = (unsigned int)__shfl_xor((int)Y1, 32, 64);
        u32x4 pw;
        pw[0] = hi ? sY0 : X0;
        pw[1] = hi ? sY1 : X1;
        pw[2] = hi ? Y0 : sX0;
        pw[3] = hi ? Y1 : sX1;
        pa[ks] = __builtin_bit_cast(bf16x8, pw);
      }

      // PV
#pragma unroll
      for (int dt = 0; dt < 4; ++dt) {
        acc[dt] = __builtin_amdgcn_mfma_f32_32x32x16_bf16(pa[0], vf[dt][0], acc[dt], 0, 0, 0);
        acc[dt] = __builtin_amdgcn_mfma_f32_32x32x16_bf16(pa[1], vf[dt][1], acc[dt], 0, 0, 0);
      }
    }

    // ---- merge the two waves' partials for this tile ----
    if (hi == 0) { mbuf[w][ln] = m_run; lbuf[w][ln] = l_run; }
    __syncthreads();

    const int wW = (s == 0) ? 1 : 0;   // writer wave (other wave combines+stores)
    if (w == wW) {
#pragma unroll
      for (int r = 0; r < 16; ++r) {
        const int row = (r & 3) + 8 * (r >> 2) + 4 * hi;
        float m0 = mbuf[0][row], m1 = mbuf[1][row];
        float ms = fmaxf(m0, m1);
        float fown = exp2f(((w ? m1 : m0) - ms) * SCL);
#pragma unroll
        for (int dt = 0; dt < 4; ++dt)
          abuf[(dt * 16 + r) * 64 + lane] = acc[dt][r] * fown;
      }
    }
    __syncthreads();
    if (w != wW) {
#pragma unroll
      for (int r = 0; r < 16; ++r) {
        const int row = (r & 3) + 8 * (r >> 2) + 4 * hi;
        float m0 = mbuf[0][row], m1 = mbuf[1][row];
        float ms = fmaxf(m0, m1);
        float f0 = exp2f((m0 - ms) * SCL);
        float f1 = exp2f((m1 - ms) * SCL);
        float ls = lbuf[0][row] * f0 + lbuf[1][row] * f1;
        float inv = 1.0f / ls;
        float fown = w ? f1 : f0;
        const int qg = q0 + row;
        unsigned short* op = Out + (size_t)qg * DMODEL + h * 128 + ln;
#pragma unroll
        for (int dt = 0; dt < 4; ++dt) {
          float val = (acc[dt][r] * fown + abuf[(dt * 16 + r) * 64 + lane]) * inv;
          op[dt * 32] = f2bf(val);
        }
      }
    }
    __syncthreads();
  }
}

// ---------------- launch ----------------
extern "C" void kernel_launch(void* const* d_in, const int* in_sizes, int n_in,
                              void* d_out, int out_size, void* d_ws, size_t ws_size,
                              hipStream_t stream) {
  (void)in_sizes; (void)n_in; (void)out_size; (void)ws_size;
  const float* x  = (const float*)d_in[0];
  const float* fc = (const float*)d_in[1];
  const float* fs = (const float*)d_in[2];
  const float* wq = (const float*)d_in[5];
  const float* wk = (const float*)d_in[6];
  const float* wv = (const float*)d_in[7];
  const float* wo = (const float*)d_in[8];
  float* out = (float*)d_out;

  char* ws = (char*)d_ws;
  const size_t MB = 1ull << 20;
  unsigned short* xb    = (unsigned short*)(ws + 0);        // 16MB
  unsigned short* wqb   = (unsigned short*)(ws + 16 * MB);  // 32MB
  unsigned short* wkb   = (unsigned short*)(ws + 48 * MB);  // 8MB
  unsigned short* wvb   = (unsigned short*)(ws + 56 * MB);  // 8MB
  float*          Qf    = (float*)(ws + 64 * MB);           // 32MB
  float*          Kf    = (float*)(ws + 96 * MB);           // 8MB
  float*          Vf    = (float*)(ws + 104 * MB);          // 8MB
  unsigned short* Qhb   = (unsigned short*)(ws + 112 * MB); // 16MB
  unsigned short* Khb   = (unsigned short*)(ws + 128 * MB); // 4MB
  unsigned short* VTb   = (unsigned short*)(ws + 132 * MB); // 4MB
  unsigned short* attnb = (unsigned short*)(ws + 64 * MB);  // reuse Qf
  unsigned short* wob   = (unsigned short*)(ws + 16 * MB);  // reuse wqb

  // fused converts: x (2M f32x4), wq (4M), wk (1M), wv (1M) = 8M -> 32768 blocks
  cvt_bf16_multi<<<32768, 256, 0, stream>>>(x, xb, 2097152,
                                            wq, wqb, 4194304,
                                            wk, wkb, 1048576,
                                            wv, wvb, 1048576);

  gemm_bt<<<dim3(16, 32), 256, 0, stream>>>(xb, wqb, Qf, 4096);
  gemm_bt_kv<<<dim3(16, 16), 256, 0, stream>>>(xb, wkb, wvb, Kf, Vf);

  cvt_bf16<<<16384, 256, 0, stream>>>(wo, wob, 16777216 / 4);

  rope_relayout<<<16384, 256, 0, stream>>>(Qf, fc, fs, Qhb, 32, 4096);
  rope_relayout<<<4096, 256, 0, stream>>>(Kf, fc, fs, Khb, 8, 1024);
  v_transpose<<<dim3(64, 32), 256, 0, stream>>>(Vf, VTb);

  attn_kernel<<<1024, 128, 0, stream>>>(Qhb, Khb, VTb, attnb);

  gemm_bt<<<dim3(16, 32), 256, 0, stream>>>(attnb, wob, out, 4096);
}

// Round 4
// 578.581 us; speedup vs baseline: 1.2952x; 1.2952x over previous
//
#include <hip/hip_runtime.h>

typedef __attribute__((ext_vector_type(4))) float f32x4;
typedef __attribute__((ext_vector_type(16))) float f32x16;
typedef __attribute__((ext_vector_type(8))) short bf16x8;
typedef __attribute__((ext_vector_type(4))) unsigned short u16x4;
typedef __attribute__((ext_vector_type(2))) unsigned short u16x2;
typedef __attribute__((ext_vector_type(4))) unsigned int u32x4;

#define SEQ 2048
#define DMODEL 4096

__device__ __forceinline__ unsigned short f2bf(float f) {
  unsigned int u = __float_as_uint(f);
  u += 0x7FFFu + ((u >> 16) & 1u);   // RNE
  return (unsigned short)(u >> 16);
}

__device__ __forceinline__ void gload_lds16(const unsigned short* g, unsigned short* l) {
  __builtin_amdgcn_global_load_lds(
      (const __attribute__((address_space(1))) unsigned int*)g,
      (__attribute__((address_space(3))) unsigned int*)l, 16, 0, 0);
}

__device__ __forceinline__ unsigned int cvt_pk_bf16(float lo, float hi) {
  unsigned int r;
  asm("v_cvt_pk_bf16_f32 %0, %1, %2" : "=v"(r) : "v"(lo), "v"(hi));
  return r;
}

// ---------------- fused fp32 -> bf16 converts (x, wq, wk, wv) ----------------
__global__ __launch_bounds__(256) void cvt_bf16_multi(
    const float* __restrict__ s0, unsigned short* __restrict__ d0, int n0,
    const float* __restrict__ s1, unsigned short* __restrict__ d1, int n1,
    const float* __restrict__ s2, unsigned short* __restrict__ d2, int n2,
    const float* __restrict__ s3, unsigned short* __restrict__ d3, int n3) {
  int i = blockIdx.x * 256 + threadIdx.x;
  const float* s; unsigned short* d; int j = i;
  if (j < n0) { s = s0; d = d0; }
  else if ((j -= n0) < n1) { s = s1; d = d1; }
  else if ((j -= n1) < n2) { s = s2; d = d2; }
  else if ((j -= n2) < n3) { s = s3; d = d3; }
  else return;
  f32x4 v = *(const f32x4*)(s + (size_t)j * 4);
  u16x4 o;
  o[0] = f2bf(v[0]); o[1] = f2bf(v[1]); o[2] = f2bf(v[2]); o[3] = f2bf(v[3]);
  *(u16x4*)(d + (size_t)j * 4) = o;
}

__global__ __launch_bounds__(256) void cvt_bf16(const float* __restrict__ in,
                                                unsigned short* __restrict__ out, int n4) {
  int i = blockIdx.x * 256 + threadIdx.x;
  if (i >= n4) return;
  f32x4 v = *(const f32x4*)(in + (size_t)i * 4);
  u16x4 o;
  o[0] = f2bf(v[0]); o[1] = f2bf(v[1]); o[2] = f2bf(v[2]); o[3] = f2bf(v[3]);
  *(u16x4*)(out + (size_t)i * 4) = o;
}

// ---------------- bf16 GEMM body, C = A[M,K] * B[N,K]^T, K=4096 ----------------
__device__ __forceinline__ void gemm_bt_body(const unsigned short* __restrict__ A,
                                             const unsigned short* __restrict__ B,
                                             float* __restrict__ C, int N,
                                             int bm, int bn) {
  __shared__ unsigned short As[128 * 64];
  __shared__ unsigned short Bs[128 * 64];
  const int K = 4096;
  const int t = threadIdx.x;
  const int lane = t & 63, w = t >> 6;
  const int wm = w >> 1, wn = w & 1;
  const int g = lane >> 4, q = lane & 15;

  const int srow = t >> 3;
  const int slb = (t & 7) ^ (srow & 7);
  const unsigned short* gA = A + (size_t)(bm * 128 + srow) * K + slb * 8;
  const unsigned short* gB = B + (size_t)(bn * 128 + srow) * K + slb * 8;
  unsigned short* lA = As + t * 8;
  unsigned short* lB = Bs + t * 8;

  f32x4 acc[4][4];
  for (int i = 0; i < 4; ++i)
    for (int j = 0; j < 4; ++j)
      for (int r = 0; r < 4; ++r) acc[i][j][r] = 0.f;

  for (int k0 = 0; k0 < K; k0 += 64) {
#pragma unroll
    for (int i = 0; i < 4; ++i) {
      gload_lds16(gA + (size_t)i * 32 * K + k0, lA + i * 2048);
      gload_lds16(gB + (size_t)i * 32 * K + k0, lB + i * 2048);
    }
    __syncthreads();
#pragma unroll
    for (int kk = 0; kk < 2; ++kk) {
      bf16x8 af[4], bfr[4];
#pragma unroll
      for (int i = 0; i < 4; ++i) {
        const int ra = wm * 64 + i * 16 + q;
        af[i] = *(const bf16x8*)&As[ra * 64 + (((kk * 4 + g) ^ (ra & 7)) * 8)];
        const int rb = wn * 64 + i * 16 + q;
        bfr[i] = *(const bf16x8*)&Bs[rb * 64 + (((kk * 4 + g) ^ (rb & 7)) * 8)];
      }
#pragma unroll
      for (int i = 0; i < 4; ++i)
#pragma unroll
        for (int j = 0; j < 4; ++j)
          acc[i][j] = __builtin_amdgcn_mfma_f32_16x16x32_bf16(af[i], bfr[j], acc[i][j], 0, 0, 0);
    }
    __syncthreads();
  }

  const int crow0 = bm * 128 + wm * 64 + g * 4;
  const int ccol0 = bn * 128 + wn * 64 + q;
#pragma unroll
  for (int i = 0; i < 4; ++i)
#pragma unroll
    for (int j = 0; j < 4; ++j) {
      float* cp = C + (size_t)(crow0 + i * 16) * N + ccol0 + j * 16;
#pragma unroll
      for (int r = 0; r < 4; ++r) cp[(size_t)r * N] = acc[i][j][r];
    }
}

__global__ __launch_bounds__(256) void gemm_bt(const unsigned short* __restrict__ A,
                                               const unsigned short* __restrict__ B,
                                               float* __restrict__ C, int N) {
  gemm_bt_body(A, B, C, N, blockIdx.x, blockIdx.y);
}

// fused K+V projection: grid (16, 16); bn<8 -> K, else V (both N=1024)
__global__ __launch_bounds__(256) void gemm_bt_kv(const unsigned short* __restrict__ A,
                                                  const unsigned short* __restrict__ BK,
                                                  const unsigned short* __restrict__ BV,
                                                  float* __restrict__ CK,
                                                  float* __restrict__ CV) {
  const int bn = blockIdx.y;
  if (bn < 8) gemm_bt_body(A, BK, CK, 1024, blockIdx.x, bn);
  else        gemm_bt_body(A, BV, CV, 1024, blockIdx.x, bn - 8);
}

// ---------------- RoPE + relayout to head-major bf16 [h][S][128] ----------------
__global__ __launch_bounds__(256) void rope_relayout(const float* __restrict__ X,
                                                     const float* __restrict__ cosT,
                                                     const float* __restrict__ sinT,
                                                     unsigned short* __restrict__ out,
                                                     int nheads, int ld) {
  int idx = blockIdx.x * 256 + threadIdx.x;
  int m = idx & 63;
  int h = (idx >> 6) % nheads;
  int s = idx / (nheads * 64);
  if (s >= SEQ) return;
  const float* xp = X + (size_t)s * ld + h * 128 + 2 * m;
  float re = xp[0], im = xp[1];
  float c = cosT[s * 64 + m], sn = sinT[s * 64 + m];
  u16x2 o;
  o[0] = f2bf(re * c - im * sn);
  o[1] = f2bf(re * sn + im * c);
  *(u16x2*)(out + ((size_t)h * SEQ + s) * 128 + 2 * m) = o;
}

// ---------------- V transpose: Vf[s][1024] f32 -> VT[d][s] bf16 ----------------
__global__ __launch_bounds__(256) void v_transpose(const float* __restrict__ Vf,
                                                   unsigned short* __restrict__ VT) {
  __shared__ float tile[32][33];
  int s0 = blockIdx.x * 32, d0 = blockIdx.y * 32;
  int tx = threadIdx.x & 31, ty = threadIdx.x >> 5;
  for (int i = ty; i < 32; i += 8)
    tile[i][tx] = Vf[(size_t)(s0 + i) * 1024 + d0 + tx];
  __syncthreads();
  for (int i = ty; i < 32; i += 8)
    VT[(size_t)(d0 + i) * SEQ + s0 + tx] = f2bf(tile[tx][i]);
}

// ---------------- Flash attention, balanced split+pair, 2-wave blocks ----------
// 1024 blocks x 128 thr. Block b: kv-head = b&7 (XCD-local), q-head sub (b>>3)&3,
// pair p = b>>5. Tiles A=p, B=63-p (32 q-rows each). Each tile's causal range is
// split in half across the two waves; pairing makes every wave ~32-33 iters.
// Per-tile merge of (m,l,acc) partials through LDS.
// launch_bounds (128, 2): VGPR cap 256 — (128,4) squeezed to 64 VGPR and the
// f32x16 accumulators spilled to scratch (R3: 1.07 GB HBM/dispatch, 312 us).
__global__ __launch_bounds__(128, 2) void attn_kernel(const unsigned short* __restrict__ Qh,
                                                      const unsigned short* __restrict__ Kh,
                                                      const unsigned short* __restrict__ VT,
                                                      unsigned short* __restrict__ Out) {
  __shared__ float mbuf[2][32];
  __shared__ float lbuf[2][32];
  __shared__ float abuf[64 * 64];

  const int b = blockIdx.x;
  const int h = (b & 7) * 4 + ((b >> 3) & 3);
  const int p = b >> 5;
  const int kvh = h >> 2;
  const int t = threadIdx.x, w = t >> 6, lane = t & 63;
  const int ln = lane & 31, hi = lane >> 5;

  const unsigned short* Kp = Kh + ((size_t)kvh * SEQ + ln) * 128 + hi * 8;
  const unsigned short* Vp = VT + ((size_t)(kvh * 128 + ln)) * SEQ + hi * 8;
  const float SCL = 0.08838834764831845f * 1.44269504088896f;  // scale * log2(e)

  const int nA = p + 1, nB = 64 - p;
  const int loA = (nA + 1) >> 1, loB = (nB + 1) >> 1;

  for (int s = 0; s < 2; ++s) {
    const int tile = (s == 0) ? p : 63 - p;
    const int q0 = tile * 32;
    int kbeg, kend;
    if (s == 0) { kbeg = w ? loA : 0;  kend = w ? nA : loA; }
    else        { kbeg = w ? 0 : loB;  kend = w ? loB : nB; }

    const unsigned short* Qp = Qh + ((size_t)h * SEQ + q0 + ln) * 128 + hi * 8;
    bf16x8 qf[8];
#pragma unroll
    for (int ds = 0; ds < 8; ++ds) qf[ds] = *(const bf16x8*)(Qp + ds * 16);

    f32x16 acc[4];
#pragma unroll
    for (int dt = 0; dt < 4; ++dt)
#pragma unroll
      for (int r = 0; r < 16; ++r) acc[dt][r] = 0.f;
    float m_run = -1e30f, l_run = 0.f;

    for (int kc = kbeg; kc < kend; ++kc) {
      const int k0 = kc * 32;
      // V frags issued early (latency hides under QK^T + softmax)
      bf16x8 vf[4][2];
#pragma unroll
      for (int dt = 0; dt < 4; ++dt)
#pragma unroll
        for (int ks = 0; ks < 2; ++ks)
          vf[dt][ks] = *(const bf16x8*)(Vp + (size_t)dt * 32 * SEQ + k0 + ks * 16);

      // QK^T (two independent chains)
      bf16x8 kf[8];
      const unsigned short* kp = Kp + (size_t)k0 * 128;
#pragma unroll
      for (int ds = 0; ds < 8; ++ds) kf[ds] = *(const bf16x8*)(kp + ds * 16);
      f32x16 s0v, s1v;
#pragma unroll
      for (int r = 0; r < 16; ++r) { s0v[r] = 0.f; s1v[r] = 0.f; }
#pragma unroll
      for (int ds = 0; ds < 4; ++ds) {
        s0v = __builtin_amdgcn_mfma_f32_32x32x16_bf16(kf[ds], qf[ds], s0v, 0, 0, 0);
        s1v = __builtin_amdgcn_mfma_f32_32x32x16_bf16(kf[ds + 4], qf[ds + 4], s1v, 0, 0, 0);
      }

      // mask + in-register softmax (rows k = (r&3)+8*(r>>2)+4*hi)
      float sv[16];
#pragma unroll
      for (int r = 0; r < 16; ++r) {
        int kg = k0 + (r & 3) + 8 * (r >> 2) + 4 * hi;
        float vv = s0v[r] + s1v[r];
        sv[r] = (kg <= q0 + ln) ? vv : -1e30f;
      }
      float mx01 = fmaxf(sv[0], sv[1]), mx23 = fmaxf(sv[2], sv[3]);
      float mx45 = fmaxf(sv[4], sv[5]), mx67 = fmaxf(sv[6], sv[7]);
      float mx89 = fmaxf(sv[8], sv[9]), mxab = fmaxf(sv[10], sv[11]);
      float mxcd = fmaxf(sv[12], sv[13]), mxef = fmaxf(sv[14], sv[15]);
      float pm = fmaxf(fmaxf(fmaxf(mx01, mx23), fmaxf(mx45, mx67)),
                       fmaxf(fmaxf(mx89, mxab), fmaxf(mxcd, mxef)));
      pm = fmaxf(pm, __shfl_xor(pm, 32, 64));

      // defer-max rescale (THR = 8 log2-units)
      if (__any((pm - m_run) * SCL > 8.f)) {
        float m_new = fmaxf(m_run, pm);
        float corr = exp2f((m_run - m_new) * SCL);
        l_run *= corr;
#pragma unroll
        for (int r = 0; r < 16; ++r) {
          float cf = __shfl(corr, (r & 3) + 8 * (r >> 2) + 4 * hi, 64);
          acc[0][r] *= cf; acc[1][r] *= cf; acc[2][r] *= cf; acc[3][r] *= cf;
        }
        m_run = m_new;
      }

      // P = exp2((s - m) * SCL), row-sum
      float pv[16];
#pragma unroll
      for (int r = 0; r < 16; ++r) pv[r] = exp2f((sv[r] - m_run) * SCL);
      float a0 = (pv[0] + pv[1]) + (pv[2] + pv[3]);
      float a1 = (pv[4] + pv[5]) + (pv[6] + pv[7]);
      float a2 = (pv[8] + pv[9]) + (pv[10] + pv[11]);
      float a3 = (pv[12] + pv[13]) + (pv[14] + pv[15]);
      float ps = (a0 + a1) + (a2 + a3);
      ps += __shfl_xor(ps, 32, 64);
      l_run += ps;

      // pack P into PV A-frags: k = 16*ks + 8*hi + j
      bf16x8 pa[2];
#pragma unroll
      for (int ks = 0; ks < 2; ++ks) {
        unsigned int X0 = cvt_pk_bf16(pv[8 * ks + 0], pv[8 * ks + 1]);
        unsigned int X1 = cvt_pk_bf16(pv[8 * ks + 2], pv[8 * ks + 3]);
        unsigned int Y0 = cvt_pk_bf16(pv[8 * ks + 4], pv[8 * ks + 5]);
        unsigned int Y1 = cvt_pk_bf16(pv[8 * ks + 6], pv[8 * ks + 7]);
        unsigned int sX0 = (unsigned int)__shfl_xor((int)X0, 32, 64);
        unsigned int sX1 = (unsigned int)__shfl_xor((int)X1, 32, 64);
        unsigned int sY0 = (unsigned int)__shfl_xor((int)Y0, 32, 64);
        unsigned int sY1 = (unsigned int)__shfl_xor((int)Y1, 32, 64);
        u32x4 pw;
        pw[0] = hi ? sY0 : X0;
        pw[1] = hi ? sY1 : X1;
        pw[2] = hi ? Y0 : sX0;
        pw[3] = hi ? Y1 : sX1;
        pa[ks] = __builtin_bit_cast(bf16x8, pw);
      }

      // PV
#pragma unroll
      for (int dt = 0; dt < 4; ++dt) {
        acc[dt] = __builtin_amdgcn_mfma_f32_32x32x16_bf16(pa[0], vf[dt][0], acc[dt], 0, 0, 0);
        acc[dt] = __builtin_amdgcn_mfma_f32_32x32x16_bf16(pa[1], vf[dt][1], acc[dt], 0, 0, 0);
      }
    }

    // ---- merge the two waves' partials for this tile ----
    if (hi == 0) { mbuf[w][ln] = m_run; lbuf[w][ln] = l_run; }
    __syncthreads();

    const int wW = (s == 0) ? 1 : 0;   // writer wave (other wave combines+stores)
    if (w == wW) {
#pragma unroll
      for (int r = 0; r < 16; ++r) {
        const int row = (r & 3) + 8 * (r >> 2) + 4 * hi;
        float m0 = mbuf[0][row], m1 = mbuf[1][row];
        float ms = fmaxf(m0, m1);
        float fown = exp2f(((w ? m1 : m0) - ms) * SCL);
#pragma unroll
        for (int dt = 0; dt < 4; ++dt)
          abuf[(dt * 16 + r) * 64 + lane] = acc[dt][r] * fown;
      }
    }
    __syncthreads();
    if (w != wW) {
#pragma unroll
      for (int r = 0; r < 16; ++r) {
        const int row = (r & 3) + 8 * (r >> 2) + 4 * hi;
        float m0 = mbuf[0][row], m1 = mbuf[1][row];
        float ms = fmaxf(m0, m1);
        float f0 = exp2f((m0 - ms) * SCL);
        float f1 = exp2f((m1 - ms) * SCL);
        float ls = lbuf[0][row] * f0 + lbuf[1][row] * f1;
        float inv = 1.0f / ls;
        float fown = w ? f1 : f0;
        const int qg = q0 + row;
        unsigned short* op = Out + (size_t)qg * DMODEL + h * 128 + ln;
#pragma unroll
        for (int dt = 0; dt < 4; ++dt) {
          float val = (acc[dt][r] * fown + abuf[(dt * 16 + r) * 64 + lane]) * inv;
          op[dt * 32] = f2bf(val);
        }
      }
    }
    __syncthreads();
  }
}

// ---------------- launch ----------------
extern "C" void kernel_launch(void* const* d_in, const int* in_sizes, int n_in,
                              void* d_out, int out_size, void* d_ws, size_t ws_size,
                              hipStream_t stream) {
  (void)in_sizes; (void)n_in; (void)out_size; (void)ws_size;
  const float* x  = (const float*)d_in[0];
  const float* fc = (const float*)d_in[1];
  const float* fs = (const float*)d_in[2];
  const float* wq = (const float*)d_in[5];
  const float* wk = (const float*)d_in[6];
  const float* wv = (const float*)d_in[7];
  const float* wo = (const float*)d_in[8];
  float* out = (float*)d_out;

  char* ws = (char*)d_ws;
  const size_t MB = 1ull << 20;
  unsigned short* xb    = (unsigned short*)(ws + 0);        // 16MB
  unsigned short* wqb   = (unsigned short*)(ws + 16 * MB);  // 32MB
  unsigned short* wkb   = (unsigned short*)(ws + 48 * MB);  // 8MB
  unsigned short* wvb   = (unsigned short*)(ws + 56 * MB);  // 8MB
  float*          Qf    = (float*)(ws + 64 * MB);           // 32MB
  float*          Kf    = (float*)(ws + 96 * MB);           // 8MB
  float*          Vf    = (float*)(ws + 104 * MB);          // 8MB
  unsigned short* Qhb   = (unsigned short*)(ws + 112 * MB); // 16MB
  unsigned short* Khb   = (unsigned short*)(ws + 128 * MB); // 4MB
  unsigned short* VTb   = (unsigned short*)(ws + 132 * MB); // 4MB
  unsigned short* attnb = (unsigned short*)(ws + 64 * MB);  // reuse Qf
  unsigned short* wob   = (unsigned short*)(ws + 16 * MB);  // reuse wqb

  // fused converts: x (2M f32x4), wq (4M), wk (1M), wv (1M) = 8M -> 32768 blocks
  cvt_bf16_multi<<<32768, 256, 0, stream>>>(x, xb, 2097152,
                                            wq, wqb, 4194304,
                                            wk, wkb, 1048576,
                                            wv, wvb, 1048576);

  gemm_bt<<<dim3(16, 32), 256, 0, stream>>>(xb, wqb, Qf, 4096);
  gemm_bt_kv<<<dim3(16, 16), 256, 0, stream>>>(xb, wkb, wvb, Kf, Vf);

  cvt_bf16<<<16384, 256, 0, stream>>>(wo, wob, 16777216 / 4);

  rope_relayout<<<16384, 256, 0, stream>>>(Qf, fc, fs, Qhb, 32, 4096);
  rope_relayout<<<4096, 256, 0, stream>>>(Kf, fc, fs, Khb, 8, 1024);
  v_transpose<<<dim3(64, 32), 256, 0, stream>>>(Vf, VTb);

  attn_kernel<<<1024, 128, 0, stream>>>(Qhb, Khb, VTb, attnb);

  gemm_bt<<<dim3(16, 32), 256, 0, stream>>>(attnb, wob, out, 4096);
}

// Round 5
// 574.849 us; speedup vs baseline: 1.3036x; 1.0065x over previous
//
#include <hip/hip_runtime.h>

typedef __attribute__((ext_vector_type(4))) float f32x4;
typedef __attribute__((ext_vector_type(16))) float f32x16;
typedef __attribute__((ext_vector_type(8))) short bf16x8;
typedef __attribute__((ext_vector_type(4))) unsigned short u16x4;
typedef __attribute__((ext_vector_type(2))) unsigned short u16x2;
typedef __attribute__((ext_vector_type(4))) unsigned int u32x4;

#define SEQ 2048
#define DMODEL 4096

__device__ __forceinline__ unsigned short f2bf(float f) {
  unsigned int u = __float_as_uint(f);
  u += 0x7FFFu + ((u >> 16) & 1u);   // RNE
  return (unsigned short)(u >> 16);
}

__device__ __forceinline__ void gload_lds16(const unsigned short* g, unsigned short* l) {
  __builtin_amdgcn_global_load_lds(
      (const __attribute__((address_space(1))) unsigned int*)g,
      (__attribute__((address_space(3))) unsigned int*)l, 16, 0, 0);
}

__device__ __forceinline__ unsigned int cvt_pk_bf16(float lo, float hi) {
  unsigned int r;
  asm("v_cvt_pk_bf16_f32 %0, %1, %2" : "=v"(r) : "v"(lo), "v"(hi));
  return r;
}

// ---------------- fused fp32 -> bf16 converts (x, wq, wk, wv) ----------------
__global__ __launch_bounds__(256) void cvt_bf16_multi(
    const float* __restrict__ s0, unsigned short* __restrict__ d0, int n0,
    const float* __restrict__ s1, unsigned short* __restrict__ d1, int n1,
    const float* __restrict__ s2, unsigned short* __restrict__ d2, int n2,
    const float* __restrict__ s3, unsigned short* __restrict__ d3, int n3) {
  int i = blockIdx.x * 256 + threadIdx.x;
  const float* s; unsigned short* d; int j = i;
  if (j < n0) { s = s0; d = d0; }
  else if ((j -= n0) < n1) { s = s1; d = d1; }
  else if ((j -= n1) < n2) { s = s2; d = d2; }
  else if ((j -= n2) < n3) { s = s3; d = d3; }
  else return;
  f32x4 v = *(const f32x4*)(s + (size_t)j * 4);
  u16x4 o;
  o[0] = f2bf(v[0]); o[1] = f2bf(v[1]); o[2] = f2bf(v[2]); o[3] = f2bf(v[3]);
  *(u16x4*)(d + (size_t)j * 4) = o;
}

__global__ __launch_bounds__(256) void cvt_bf16(const float* __restrict__ in,
                                                unsigned short* __restrict__ out, int n4) {
  int i = blockIdx.x * 256 + threadIdx.x;
  if (i >= n4) return;
  f32x4 v = *(const f32x4*)(in + (size_t)i * 4);
  u16x4 o;
  o[0] = f2bf(v[0]); o[1] = f2bf(v[1]); o[2] = f2bf(v[2]); o[3] = f2bf(v[3]);
  *(u16x4*)(out + (size_t)i * 4) = o;
}

// ---------------- bf16 GEMM body, C = A[M,K] * B[N,K]^T, K=4096 ----------------
__device__ __forceinline__ void gemm_bt_body(const unsigned short* __restrict__ A,
                                             const unsigned short* __restrict__ B,
                                             float* __restrict__ C, int N,
                                             int bm, int bn) {
  __shared__ unsigned short As[128 * 64];
  __shared__ unsigned short Bs[128 * 64];
  const int K = 4096;
  const int t = threadIdx.x;
  const int lane = t & 63, w = t >> 6;
  const int wm = w >> 1, wn = w & 1;
  const int g = lane >> 4, q = lane & 15;

  const int srow = t >> 3;
  const int slb = (t & 7) ^ (srow & 7);
  const unsigned short* gA = A + (size_t)(bm * 128 + srow) * K + slb * 8;
  const unsigned short* gB = B + (size_t)(bn * 128 + srow) * K + slb * 8;
  unsigned short* lA = As + t * 8;
  unsigned short* lB = Bs + t * 8;

  f32x4 acc[4][4];
  for (int i = 0; i < 4; ++i)
    for (int j = 0; j < 4; ++j)
      for (int r = 0; r < 4; ++r) acc[i][j][r] = 0.f;

  for (int k0 = 0; k0 < K; k0 += 64) {
#pragma unroll
    for (int i = 0; i < 4; ++i) {
      gload_lds16(gA + (size_t)i * 32 * K + k0, lA + i * 2048);
      gload_lds16(gB + (size_t)i * 32 * K + k0, lB + i * 2048);
    }
    __syncthreads();
#pragma unroll
    for (int kk = 0; kk < 2; ++kk) {
      bf16x8 af[4], bfr[4];
#pragma unroll
      for (int i = 0; i < 4; ++i) {
        const int ra = wm * 64 + i * 16 + q;
        af[i] = *(const bf16x8*)&As[ra * 64 + (((kk * 4 + g) ^ (ra & 7)) * 8)];
        const int rb = wn * 64 + i * 16 + q;
        bfr[i] = *(const bf16x8*)&Bs[rb * 64 + (((kk * 4 + g) ^ (rb & 7)) * 8)];
      }
#pragma unroll
      for (int i = 0; i < 4; ++i)
#pragma unroll
        for (int j = 0; j < 4; ++j)
          acc[i][j] = __builtin_amdgcn_mfma_f32_16x16x32_bf16(af[i], bfr[j], acc[i][j], 0, 0, 0);
    }
    __syncthreads();
  }

  const int crow0 = bm * 128 + wm * 64 + g * 4;
  const int ccol0 = bn * 128 + wn * 64 + q;
#pragma unroll
  for (int i = 0; i < 4; ++i)
#pragma unroll
    for (int j = 0; j < 4; ++j) {
      float* cp = C + (size_t)(crow0 + i * 16) * N + ccol0 + j * 16;
#pragma unroll
      for (int r = 0; r < 4; ++r) cp[(size_t)r * N] = acc[i][j][r];
    }
}

__global__ __launch_bounds__(256) void gemm_bt(const unsigned short* __restrict__ A,
                                               const unsigned short* __restrict__ B,
                                               float* __restrict__ C, int N) {
  gemm_bt_body(A, B, C, N, blockIdx.x, blockIdx.y);
}

// fused K+V projection: grid (16, 16); bn<8 -> K, else V (both N=1024)
__global__ __launch_bounds__(256) void gemm_bt_kv(const unsigned short* __restrict__ A,
                                                  const unsigned short* __restrict__ BK,
                                                  const unsigned short* __restrict__ BV,
                                                  float* __restrict__ CK,
                                                  float* __restrict__ CV) {
  const int bn = blockIdx.y;
  if (bn < 8) gemm_bt_body(A, BK, CK, 1024, blockIdx.x, bn);
  else        gemm_bt_body(A, BV, CV, 1024, blockIdx.x, bn - 8);
}

// ---------------- RoPE + relayout to head-major bf16 [h][S][128] ----------------
__global__ __launch_bounds__(256) void rope_relayout(const float* __restrict__ X,
                                                     const float* __restrict__ cosT,
                                                     const float* __restrict__ sinT,
                                                     unsigned short* __restrict__ out,
                                                     int nheads, int ld) {
  int idx = blockIdx.x * 256 + threadIdx.x;
  int m = idx & 63;
  int h = (idx >> 6) % nheads;
  int s = idx / (nheads * 64);
  if (s >= SEQ) return;
  const float* xp = X + (size_t)s * ld + h * 128 + 2 * m;
  float re = xp[0], im = xp[1];
  float c = cosT[s * 64 + m], sn = sinT[s * 64 + m];
  u16x2 o;
  o[0] = f2bf(re * c - im * sn);
  o[1] = f2bf(re * sn + im * c);
  *(u16x2*)(out + ((size_t)h * SEQ + s) * 128 + 2 * m) = o;
}

// ---------------- V transpose: Vf[s][1024] f32 -> VT[d][s] bf16 ----------------
__global__ __launch_bounds__(256) void v_transpose(const float* __restrict__ Vf,
                                                   unsigned short* __restrict__ VT) {
  __shared__ float tile[32][33];
  int s0 = blockIdx.x * 32, d0 = blockIdx.y * 32;
  int tx = threadIdx.x & 31, ty = threadIdx.x >> 5;
  for (int i = ty; i < 32; i += 8)
    tile[i][tx] = Vf[(size_t)(s0 + i) * 1024 + d0 + tx];
  __syncthreads();
  for (int i = ty; i < 32; i += 8)
    VT[(size_t)(d0 + i) * SEQ + s0 + tx] = f2bf(tile[tx][i]);
}

// ---------------- Flash attention, balanced split+pair, 2-wave blocks ----------
// 1024 blocks x 128 thr. Block b: kv-head = b&7 (XCD-local), q-head sub (b>>3)&3,
// pair p = b>>5. Tiles A=p, B=63-p (32 q-rows each). Each tile's causal range is
// split in half across the two waves; pairing makes every wave ~32-33 iters.
// Per-tile merge of (m,l,acc) partials through LDS.
// amdgpu_waves_per_eu(2,2): grid gives exactly 2 waves/SIMD resident; let the
// allocator use up to 256 VGPR so the 16 K/V loads per iter batch-issue.
// (R4: launch_bounds(128,2) heuristically squeezed to 128 VGPR -> serialized
// loads, ~10K cyc/iter, 138 us. 4 blk/CU x 2 waves x ~220 VGPR = 1760 < 2048.)
__global__ __launch_bounds__(128)
__attribute__((amdgpu_waves_per_eu(2, 2)))
void attn_kernel(const unsigned short* __restrict__ Qh,
                 const unsigned short* __restrict__ Kh,
                 const unsigned short* __restrict__ VT,
                 unsigned short* __restrict__ Out) {
  __shared__ float mbuf[2][32];
  __shared__ float lbuf[2][32];
  __shared__ float abuf[64 * 64];

  const int b = blockIdx.x;
  const int h = (b & 7) * 4 + ((b >> 3) & 3);
  const int p = b >> 5;
  const int kvh = h >> 2;
  const int t = threadIdx.x, w = t >> 6, lane = t & 63;
  const int ln = lane & 31, hi = lane >> 5;

  const unsigned short* Kp = Kh + ((size_t)kvh * SEQ + ln) * 128 + hi * 8;
  const unsigned short* Vp = VT + ((size_t)(kvh * 128 + ln)) * SEQ + hi * 8;
  const float SCL = 0.08838834764831845f * 1.44269504088896f;  // scale * log2(e)

  const int nA = p + 1, nB = 64 - p;
  const int loA = (nA + 1) >> 1, loB = (nB + 1) >> 1;

  for (int s = 0; s < 2; ++s) {
    const int tile = (s == 0) ? p : 63 - p;
    const int q0 = tile * 32;
    int kbeg, kend;
    if (s == 0) { kbeg = w ? loA : 0;  kend = w ? nA : loA; }
    else        { kbeg = w ? 0 : loB;  kend = w ? loB : nB; }

    const unsigned short* Qp = Qh + ((size_t)h * SEQ + q0 + ln) * 128 + hi * 8;
    bf16x8 qf[8];
#pragma unroll
    for (int ds = 0; ds < 8; ++ds) qf[ds] = *(const bf16x8*)(Qp + ds * 16);

    f32x16 acc[4];
#pragma unroll
    for (int dt = 0; dt < 4; ++dt)
#pragma unroll
      for (int r = 0; r < 16; ++r) acc[dt][r] = 0.f;
    float m_run = -1e30f, l_run = 0.f;

    for (int kc = kbeg; kc < kend; ++kc) {
      const int k0 = kc * 32;
      // V frags issued early (latency hides under QK^T + softmax)
      bf16x8 vf[4][2];
#pragma unroll
      for (int dt = 0; dt < 4; ++dt)
#pragma unroll
        for (int ks = 0; ks < 2; ++ks)
          vf[dt][ks] = *(const bf16x8*)(Vp + (size_t)dt * 32 * SEQ + k0 + ks * 16);

      // QK^T (two independent chains)
      bf16x8 kf[8];
      const unsigned short* kp = Kp + (size_t)k0 * 128;
#pragma unroll
      for (int ds = 0; ds < 8; ++ds) kf[ds] = *(const bf16x8*)(kp + ds * 16);
      f32x16 s0v, s1v;
#pragma unroll
      for (int r = 0; r < 16; ++r) { s0v[r] = 0.f; s1v[r] = 0.f; }
#pragma unroll
      for (int ds = 0; ds < 4; ++ds) {
        s0v = __builtin_amdgcn_mfma_f32_32x32x16_bf16(kf[ds], qf[ds], s0v, 0, 0, 0);
        s1v = __builtin_amdgcn_mfma_f32_32x32x16_bf16(kf[ds + 4], qf[ds + 4], s1v, 0, 0, 0);
      }

      // mask + in-register softmax (rows k = (r&3)+8*(r>>2)+4*hi)
      float sv[16];
#pragma unroll
      for (int r = 0; r < 16; ++r) {
        int kg = k0 + (r & 3) + 8 * (r >> 2) + 4 * hi;
        float vv = s0v[r] + s1v[r];
        sv[r] = (kg <= q0 + ln) ? vv : -1e30f;
      }
      float mx01 = fmaxf(sv[0], sv[1]), mx23 = fmaxf(sv[2], sv[3]);
      float mx45 = fmaxf(sv[4], sv[5]), mx67 = fmaxf(sv[6], sv[7]);
      float mx89 = fmaxf(sv[8], sv[9]), mxab = fmaxf(sv[10], sv[11]);
      float mxcd = fmaxf(sv[12], sv[13]), mxef = fmaxf(sv[14], sv[15]);
      float pm = fmaxf(fmaxf(fmaxf(mx01, mx23), fmaxf(mx45, mx67)),
                       fmaxf(fmaxf(mx89, mxab), fmaxf(mxcd, mxef)));
      pm = fmaxf(pm, __shfl_xor(pm, 32, 64));

      // defer-max rescale (THR = 8 log2-units)
      if (__any((pm - m_run) * SCL > 8.f)) {
        float m_new = fmaxf(m_run, pm);
        float corr = exp2f((m_run - m_new) * SCL);
        l_run *= corr;
#pragma unroll
        for (int r = 0; r < 16; ++r) {
          float cf = __shfl(corr, (r & 3) + 8 * (r >> 2) + 4 * hi, 64);
          acc[0][r] *= cf; acc[1][r] *= cf; acc[2][r] *= cf; acc[3][r] *= cf;
        }
        m_run = m_new;
      }

      // P = exp2((s - m) * SCL), row-sum
      float pv[16];
#pragma unroll
      for (int r = 0; r < 16; ++r) pv[r] = exp2f((sv[r] - m_run) * SCL);
      float a0 = (pv[0] + pv[1]) + (pv[2] + pv[3]);
      float a1 = (pv[4] + pv[5]) + (pv[6] + pv[7]);
      float a2 = (pv[8] + pv[9]) + (pv[10] + pv[11]);
      float a3 = (pv[12] + pv[13]) + (pv[14] + pv[15]);
      float ps = (a0 + a1) + (a2 + a3);
      ps += __shfl_xor(ps, 32, 64);
      l_run += ps;

      // pack P into PV A-frags: k = 16*ks + 8*hi + j
      bf16x8 pa[2];
#pragma unroll
      for (int ks = 0; ks < 2; ++ks) {
        unsigned int X0 = cvt_pk_bf16(pv[8 * ks + 0], pv[8 * ks + 1]);
        unsigned int X1 = cvt_pk_bf16(pv[8 * ks + 2], pv[8 * ks + 3]);
        unsigned int Y0 = cvt_pk_bf16(pv[8 * ks + 4], pv[8 * ks + 5]);
        unsigned int Y1 = cvt_pk_bf16(pv[8 * ks + 6], pv[8 * ks + 7]);
        unsigned int sX0 = (unsigned int)__shfl_xor((int)X0, 32, 64);
        unsigned int sX1 = (unsigned int)__shfl_xor((int)X1, 32, 64);
        unsigned int sY0 = (unsigned int)__shfl_xor((int)Y0, 32, 64);
        unsigned int sY1 = (unsigned int)__shfl_xor((int)Y1, 32, 64);
        u32x4 pw;
        pw[0] = hi ? sY0 : X0;
        pw[1] = hi ? sY1 : X1;
        pw[2] = hi ? Y0 : sX0;
        pw[3] = hi ? Y1 : sX1;
        pa[ks] = __builtin_bit_cast(bf16x8, pw);
      }

      // PV
#pragma unroll
      for (int dt = 0; dt < 4; ++dt) {
        acc[dt] = __builtin_amdgcn_mfma_f32_32x32x16_bf16(pa[0], vf[dt][0], acc[dt], 0, 0, 0);
        acc[dt] = __builtin_amdgcn_mfma_f32_32x32x16_bf16(pa[1], vf[dt][1], acc[dt], 0, 0, 0);
      }
    }

    // ---- merge the two waves' partials for this tile ----
    if (hi == 0) { mbuf[w][ln] = m_run; lbuf[w][ln] = l_run; }
    __syncthreads();

    const int wW = (s == 0) ? 1 : 0;   // writer wave (other wave combines+stores)
    if (w == wW) {
#pragma unroll
      for (int r = 0; r < 16; ++r) {
        const int row = (r & 3) + 8 * (r >> 2) + 4 * hi;
        float m0 = mbuf[0][row], m1 = mbuf[1][row];
        float ms = fmaxf(m0, m1);
        float fown = exp2f(((w ? m1 : m0) - ms) * SCL);
#pragma unroll
        for (int dt = 0; dt < 4; ++dt)
          abuf[(dt * 16 + r) * 64 + lane] = acc[dt][r] * fown;
      }
    }
    __syncthreads();
    if (w != wW) {
#pragma unroll
      for (int r = 0; r < 16; ++r) {
        const int row = (r & 3) + 8 * (r >> 2) + 4 * hi;
        float m0 = mbuf[0][row], m1 = mbuf[1][row];
        float ms = fmaxf(m0, m1);
        float f0 = exp2f((m0 - ms) * SCL);
        float f1 = exp2f((m1 - ms) * SCL);
        float ls = lbuf[0][row] * f0 + lbuf[1][row] * f1;
        float inv = 1.0f / ls;
        float fown = w ? f1 : f0;
        const int qg = q0 + row;
        unsigned short* op = Out + (size_t)qg * DMODEL + h * 128 + ln;
#pragma unroll
        for (int dt = 0; dt < 4; ++dt) {
          float val = (acc[dt][r] * fown + abuf[(dt * 16 + r) * 64 + lane]) * inv;
          op[dt * 32] = f2bf(val);
        }
      }
    }
    __syncthreads();
  }
}

// ---------------- launch ----------------
extern "C" void kernel_launch(void* const* d_in, const int* in_sizes, int n_in,
                              void* d_out, int out_size, void* d_ws, size_t ws_size,
                              hipStream_t stream) {
  (void)in_sizes; (void)n_in; (void)out_size; (void)ws_size;
  const float* x  = (const float*)d_in[0];
  const float* fc = (const float*)d_in[1];
  const float* fs = (const float*)d_in[2];
  const float* wq = (const float*)d_in[5];
  const float* wk = (const float*)d_in[6];
  const float* wv = (const float*)d_in[7];
  const float* wo = (const float*)d_in[8];
  float* out = (float*)d_out;

  char* ws = (char*)d_ws;
  const size_t MB = 1ull << 20;
  unsigned short* xb    = (unsigned short*)(ws + 0);        // 16MB
  unsigned short* wqb   = (unsigned short*)(ws + 16 * MB);  // 32MB
  unsigned short* wkb   = (unsigned short*)(ws + 48 * MB);  // 8MB
  unsigned short* wvb   = (unsigned short*)(ws + 56 * MB);  // 8MB
  float*          Qf    = (float*)(ws + 64 * MB);           // 32MB
  float*          Kf    = (float*)(ws + 96 * MB);           // 8MB
  float*          Vf    = (float*)(ws + 104 * MB);          // 8MB
  unsigned short* Qhb   = (unsigned short*)(ws + 112 * MB); // 16MB
  unsigned short* Khb   = (unsigned short*)(ws + 128 * MB); // 4MB
  unsigned short* VTb   = (unsigned short*)(ws + 132 * MB); // 4MB
  unsigned short* attnb = (unsigned short*)(ws + 64 * MB);  // reuse Qf
  unsigned short* wob   = (unsigned short*)(ws + 16 * MB);  // reuse wqb

  // fused converts: x (2M f32x4), wq (4M), wk (1M), wv (1M) = 8M -> 32768 blocks
  cvt_bf16_multi<<<32768, 256, 0, stream>>>(x, xb, 2097152,
                                            wq, wqb, 4194304,
                                            wk, wkb, 1048576,
                                            wv, wvb, 1048576);

  gemm_bt<<<dim3(16, 32), 256, 0, stream>>>(xb, wqb, Qf, 4096);
  gemm_bt_kv<<<dim3(16, 16), 256, 0, stream>>>(xb, wkb, wvb, Kf, Vf);

  cvt_bf16<<<16384, 256, 0, stream>>>(wo, wob, 16777216 / 4);

  rope_relayout<<<16384, 256, 0, stream>>>(Qf, fc, fs, Qhb, 32, 4096);
  rope_relayout<<<4096, 256, 0, stream>>>(Kf, fc, fs, Khb, 8, 1024);
  v_transpose<<<dim3(64, 32), 256, 0, stream>>>(Vf, VTb);

  attn_kernel<<<1024, 128, 0, stream>>>(Qhb, Khb, VTb, attnb);

  gemm_bt<<<dim3(16, 32), 256, 0, stream>>>(attnb, wob, out, 4096);
}